// Round 11
// baseline (183.401 us; speedup 1.0000x reference)
//
#include <hip/hip_runtime.h>
#include <math.h>

#define DIMH 256        // D
#define NB   32         // batch
#define E_TOT 43234
#define TE   16         // entities per block (2703 blocks = 10.6/CU)
#define DK   16         // dims per chunk
#define NCW  4          // chunks per wave (4 waves x 4 chunks x 16 dims = 256 = D)

typedef float v2f __attribute__((ext_vector_type(2)));
typedef float v4f __attribute__((ext_vector_type(4)));
typedef __fp16 v2h __attribute__((ext_vector_type(2)));
typedef __fp16 v4h __attribute__((ext_vector_type(4)));

// Kernel 1: rotate head by relation phase, emit (re0,re1,im0,im1) float4
// per (b, dpair). sincos via HW trans unit in REVOLUTIONS:
// rev = rel * 16 exactly.
__global__ __launch_bounds__(64) void rot_kernel(const float* __restrict__ head,
                                                 const float* __restrict__ rel,
                                                 float4* __restrict__ rot_v4) {
    int i  = blockIdx.x * 64 + threadIdx.x;   // 0..4095
    int b  = i >> 7;
    int dp = i & 127;
    int d0 = dp * 2;
    float4 w;
    {
        float re_h = head[b * 2 * DIMH + d0];
        float im_h = head[b * 2 * DIMH + DIMH + d0];
        float x = rel[b * DIMH + d0] * 16.0f;       // revolutions
        float f = x - floorf(x);
        float s = __builtin_amdgcn_sinf(f);
        float c = __builtin_amdgcn_cosf(f);
        w.x = re_h * c - im_h * s;                  // re(d0)
        w.z = re_h * s + im_h * c;                  // im(d0)
    }
    {
        float re_h = head[b * 2 * DIMH + d0 + 1];
        float im_h = head[b * 2 * DIMH + DIMH + d0 + 1];
        float x = rel[b * DIMH + d0 + 1] * 16.0f;
        float f = x - floorf(x);
        float s = __builtin_amdgcn_sinf(f);
        float c = __builtin_amdgcn_cosf(f);
        w.y = re_h * c - im_h * s;                  // re(d1)
        w.w = re_h * s + im_h * c;                  // im(d1)
    }
    rot_v4[b * (DIMH / 2) + dp] = w;
}

__device__ __forceinline__ v2h pkrtz(float a, float b) {
    return __builtin_amdgcn_cvt_pkrtz(a, b);
}

// ROUND-10 POST-MORTEM: wall pinned 73-79us across SIX kernels (scalar f32,
// packed f16, dot2; 8->2 B/dim LDS; occ 19-42%). Occupancy moved with zero
// wall delta -> not the lever. Busy-cycle fit with v_sqrt at quarter rate
// (16 cyc/wave): 21 cyc/wave-dim model ~= 53us measured busy. The kernel is
// ISSUE-BOUND ON THE SQRT (76% of busy cycles). ROUND 11: eliminate the
// trans op entirely — packed-f16 Newton rsqrt:
//   sqrt(s) = s * rsqrt(s); seed y0 = 0x59BA - (bits>>1) for BOTH halves
//   in one u32 op-chain (no cross-half borrow: halves <= 0x3E00 < 0x59BA);
//   one NR step in packed f16; everything v_pk_* at 2 cyc.
// 14 VALU / 2 dims = 28 cyc vs r8's measured ~47, trans pipe goes idle.
// s clamped >= f16-min-normal: kills s=0 NaN and y0^2 f16-overflow
// (y0<=248 -> yy<=61.5K<65504); clamp error <=0.008/dim. Post-NR rel err
// ~0.2% undershoot -> +~1 on dist(~450); predicted absmax ~3-5 (thr 10.48).
__device__ __forceinline__ v2h nsqrt2(v2h s) {
    const v2h eps = {(__fp16)6.104e-5f, (__fp16)6.104e-5f};   // f16 min normal
    v2h sp = __builtin_elementwise_max(s, eps);
    union { v2h h; unsigned u; } cv;
    cv.h = sp;
    union { unsigned u; v2h h; } yv;
    yv.u = 0x59BA59BAu - ((cv.u >> 1) & 0x7FFF7FFFu);         // packed seed
    v2h y = yv.h;
    const v2h cn05 = {(__fp16)-0.5f, (__fp16)-0.5f};
    const v2h c15  = {(__fp16)1.5f,  (__fp16)1.5f};
    v2h hsn = sp * cn05;
    v2h u1  = y * y * hsn + c15;     // pk_mul + pk_fma (NR correction)
    v2h y1  = y * u1;                // refined rsqrt
    return sp * y1;                  // sqrt
}

// Kernel 2: r8 structure verbatim (best counters: occ 42%, conflicts 173K,
// passed absmax 2.0): 256 thr = 4 waves; TE=16 entities x 32 batches; D
// split across waves (4 chunks of 16 dims each), wave-private 3KB LDS
// zones, zero main-loop barriers, XOR swizzle col' = p ^ (row-group),
// 2-barrier flat LDS reduction epilogue. Only the CONTRIB math changed.
__global__ __launch_bounds__(256) void dist_kernel(const float* __restrict__ ent,
                                                   const float4* __restrict__ rot_v4,
                                                   float* __restrict__ out) {
    __shared__ v4h smem[1536];   // 12288 B: 4 zones x 3 KB; reduction overlay 9.2 KB

    const int tid  = threadIdx.x;
    const int lane = tid & 63;
    const int w    = tid >> 6;
    const int eb   = blockIdx.x * TE;
    const int eg   = lane & 7;         // entity group: entities 2eg, 2eg+1
    const int bg   = lane >> 3;        // batch group: batches 4bg..4bg+3

    v4h* se = smem + w * 384;          // [16 rows][8 cols] v4h, row = entity
    v4h* sr = se + 128;                // [32 rows][8 cols] v4h, row = batch

    // staging task maps (per wave, per chunk)
    const int erow = lane >> 2;        // ent row 0..15
    const int eq   = lane & 3;         // float4-quad within the 16-dim chunk
    const int rb   = lane >> 3;        // rot batches rb, rb+8, rb+16, rb+24
    const int rdpi = lane & 7;         // dim-pair within chunk

    const int c0 = w * NCW;            // first global chunk for this wave

    float4 pe_re, pe_im, pr[4];

    auto load_chunk = [&](int c) {     // c = global chunk id (dims 16c..16c+15)
        const int dk = c * DK;
        int er = min(eb + erow, E_TOT - 1);
        const float* b0 = ent + (size_t)er * (2 * DIMH);
        pe_re = *reinterpret_cast<const float4*>(b0 + dk + 4 * eq);
        pe_im = *reinterpret_cast<const float4*>(b0 + DIMH + dk + 4 * eq);
        #pragma unroll
        for (int s = 0; s < 4; ++s)
            pr[s] = rot_v4[(rb + 8 * s) * (DIMH / 2) + c * (DK / 2) + rdpi];
    };

    auto store_chunk = [&]() {
        {
            int row = erow;
            int sw  = (row >> 1) & 7;                // 0..7
            v4h lo, hi;                              // (re0,re1,im0,im1) f16
            lo.xy = pkrtz(pe_re.x, pe_re.y);
            lo.zw = pkrtz(pe_im.x, pe_im.y);
            hi.xy = pkrtz(pe_re.z, pe_re.w);
            hi.zw = pkrtz(pe_im.z, pe_im.w);
            se[row * 8 + ((2 * eq)     ^ sw)] = lo;
            se[row * 8 + ((2 * eq + 1) ^ sw)] = hi;
        }
        #pragma unroll
        for (int s = 0; s < 4; ++s) {
            int b  = rb + 8 * s;
            int sw = (b >> 2) & 7;                   // 0..7
            v4h r;                                   // (re0,re1,im0,im1) f16
            r.xy = pkrtz(pr[s].x, pr[s].y);
            r.zw = pkrtz(pr[s].z, pr[s].w);
            sr[b * 8 + (rdpi ^ sw)] = r;
        }
    };

    v2f acc[4][2];   // f32 accumulators — static indices only
    #pragma unroll
    for (int j = 0; j < 4; ++j)
        #pragma unroll
        for (int k = 0; k < 2; ++k) { acc[j][k].x = 0.f; acc[j][k].y = 0.f; }

    load_chunk(c0);

    #pragma unroll 1
    for (int cc = 0; cc < NCW; ++cc) {
        store_chunk();                            // regs (chunk c0+cc) -> LDS
        if (cc + 1 < NCW) load_chunk(c0 + cc + 1);

        v2h a16[4][2];                            // per-chunk f16 sub-acc
        #pragma unroll
        for (int j = 0; j < 4; ++j)
            #pragma unroll
            for (int k = 0; k < 2; ++k) { a16[j][k].x = (__fp16)0.f; a16[j][k].y = (__fp16)0.f; }

        #pragma unroll 4
        for (int p = 0; p < DK / 2; ++p) {
            int pe = p ^ eg, pb = p ^ bg;
            v4h r0 = sr[(4 * bg + 0) * 8 + pb];
            v4h r1 = sr[(4 * bg + 1) * 8 + pb];
            v4h r2 = sr[(4 * bg + 2) * 8 + pb];
            v4h r3 = sr[(4 * bg + 3) * 8 + pb];
            v4h e0 = se[(2 * eg + 0) * 8 + pe];
            v4h e1 = se[(2 * eg + 1) * 8 + pe];
            // per 2 dims: 2 pk_sub + pk_mul + pk_fma + Newton-sqrt (all pk)
            #define CONTRIB(J, K, R, E)                              \
                { v2h a = R.xy - E.xy;                               \
                  v2h b = R.zw - E.zw;                               \
                  v2h s = a * a;                                     \
                  s = b * b + s;                                     \
                  a16[J][K] += nsqrt2(s); }
            CONTRIB(0,0,r0,e0) CONTRIB(0,1,r0,e1)
            CONTRIB(1,0,r1,e0) CONTRIB(1,1,r1,e1)
            CONTRIB(2,0,r2,e0) CONTRIB(2,1,r2,e1)
            CONTRIB(3,0,r3,e0) CONTRIB(3,1,r3,e1)
            #undef CONTRIB
        }

        // flush chunk sub-accumulators into f32 (bounds f16 rounding error)
        #pragma unroll
        for (int j = 0; j < 4; ++j)
            #pragma unroll
            for (int k = 0; k < 2; ++k) {
                acc[j][k].x += (float)a16[j][k].x;
                acc[j][k].y += (float)a16[j][k].y;
            }
    }

    // ---- cross-wave reduction: 4 d-partials per (b,e) ----
    float part[8];
    #pragma unroll
    for (int j = 0; j < 4; ++j)
        #pragma unroll
        for (int k = 0; k < 2; ++k)
            part[j * 2 + k] = acc[j][k].x + acc[j][k].y;

    __syncthreads();                       // all waves done reading staging LDS
    float* red = (float*)smem;             // 256 x 9 floats = 9216 B, fits
    #pragma unroll
    for (int i = 0; i < 8; ++i)
        red[tid * 9 + i] = part[i];        // stride 9: gcd(9,32)=1 -> spread
    __syncthreads();

    // 512 outputs, 2/thread; consecutive threads -> consecutive entities
    #pragma unroll
    for (int t = 0; t < 2; ++t) {
        int O  = tid + 256 * t;
        int b  = O >> 4;                   // 0..31
        int ei = O & 15;
        int e  = eb + ei;
        if (e < E_TOT) {
            int lane_src = ((b >> 2) << 3) + (ei >> 1);   // bg*8 + eg
            int idx      = ((b & 3) << 1) + (ei & 1);     // j*2 + k
            float sum = red[(0 * 64 + lane_src) * 9 + idx]
                      + red[(1 * 64 + lane_src) * 9 + idx]
                      + red[(2 * 64 + lane_src) * 9 + idx]
                      + red[(3 * 64 + lane_src) * 9 + idx];
            out[(size_t)b * E_TOT + e] = 6.0f - sum;
        }
    }
}

extern "C" void kernel_launch(void* const* d_in, const int* in_sizes, int n_in,
                              void* d_out, int out_size, void* d_ws, size_t ws_size,
                              hipStream_t stream) {
    const float* head = (const float*)d_in[0];   // (32, 512)
    const float* rel  = (const float*)d_in[1];   // (32, 256)
    const float* ent  = (const float*)d_in[2];   // (43234, 512)
    float4* rot_v4 = (float4*)d_ws;              // 32 * 128 * 16 B = 64 KB

    rot_kernel<<<(NB * DIMH / 2) / 64, 64, 0, stream>>>(head, rel, rot_v4);

    int etiles = (E_TOT + TE - 1) / TE;          // 2703
    dist_kernel<<<etiles, 256, 0, stream>>>(ent, rot_v4, (float*)d_out);
}

// Round 12
// 177.622 us; speedup vs baseline: 1.0325x; 1.0325x over previous
//
#include <hip/hip_runtime.h>
#include <math.h>

#define DIMH 256        // D
#define NB   32         // batch
#define E_TOT 43234
#define TE   32         // entities per block (1352 blocks)
#define DK   16         // dims per chunk
#define NCW  2          // chunks per wave (8 waves x 2 x 16 = 256 dims)

typedef float v2f __attribute__((ext_vector_type(2)));
typedef float v4f __attribute__((ext_vector_type(4)));
typedef __fp16 v2h __attribute__((ext_vector_type(2)));
typedef __fp16 v4h __attribute__((ext_vector_type(4)));

// Kernel 1: rotate head by relation phase; emit DIM-INTERLEAVED
// (re_d0, im_d0, re_d1, im_d1) float4 per (b, dpair) so one float4 ->
// one v4h of 2 complete dims. sincos in REVOLUTIONS: rev = rel*16 exactly.
__global__ __launch_bounds__(64) void rot_kernel(const float* __restrict__ head,
                                                 const float* __restrict__ rel,
                                                 float4* __restrict__ rot_v4) {
    int i  = blockIdx.x * 64 + threadIdx.x;   // 0..4095
    int b  = i >> 7;
    int dp = i & 127;
    int d0 = dp * 2;
    float4 w;
    {
        float re_h = head[b * 2 * DIMH + d0];
        float im_h = head[b * 2 * DIMH + DIMH + d0];
        float x = rel[b * DIMH + d0] * 16.0f;
        float f = x - floorf(x);
        float s = __builtin_amdgcn_sinf(f);
        float c = __builtin_amdgcn_cosf(f);
        w.x = re_h * c - im_h * s;                  // re(d0)
        w.y = re_h * s + im_h * c;                  // im(d0)
    }
    {
        float re_h = head[b * 2 * DIMH + d0 + 1];
        float im_h = head[b * 2 * DIMH + DIMH + d0 + 1];
        float x = rel[b * DIMH + d0 + 1] * 16.0f;
        float f = x - floorf(x);
        float s = __builtin_amdgcn_sinf(f);
        float c = __builtin_amdgcn_cosf(f);
        w.z = re_h * c - im_h * s;                  // re(d1)
        w.w = re_h * s + im_h * c;                  // im(d1)
    }
    rot_v4[b * (DIMH / 2) + dp] = w;
}

__device__ __forceinline__ v2h pkrtz(float a, float b) {
    return __builtin_amdgcn_cvt_pkrtz(a, b);
}

#if __has_builtin(__builtin_amdgcn_fdot2)
__device__ __forceinline__ float dot2(v2h a, v2h b, float c) {
    return __builtin_amdgcn_fdot2(a, b, c, false);
}
#else
__device__ __forceinline__ float dot2(v2h a, v2h b, float c) {
    return (float)a.x * (float)b.x + (float)a.y * (float)b.y + c;
}
#endif

// ROUND-11 POST-MORTEM: Newton-rsqrt (+5 VALU, -1 trans per CONTRIB) made
// wall WORSE by exactly the VALU-issue cost (+15.8us) -> trans sqrt is
// FREE (overlapped); kernel = sum of VALU-issue (~20us) + DS-pipe (~20us,
// byte-limited 85B/cyc/CU) + fixed, with poor overlap at 3.4 waves/SIMD.
// ROUND 12 attacks all three scaling terms:
//  - cheapest verified math (r9): pk_sub x2 + dot2 x2 + trans-sqrt(free)
//    + add x2 = 6 VALU / 2 dims, direct f32 acc (no subacc flush)
//  - 4b x 4e register tile: 8 ds_read_b64 feed 32 dims = 2 B/dim (r8: 3)
//  - 8-wave 512-thr blocks at TE=32: ~24 waves/CU (r8: 13.4) so VALU/DS/
//    trans pipes can actually overlap
// Wave w owns dims [32w, 32w+32) = 2 chunks of 16; wave-private 4KB LDS
// zone; zero main-loop barriers. Swizzle col^(row>>2) on store AND read:
// read rows 4g+j share (row>>2)=g -> 8 groups hit 8 distinct bank-pairs,
// 8-lane broadcast each; store spreads evenly. NO launch_bounds min arg
// (r2/r3 spill trap).
__global__ __launch_bounds__(512) void dist_kernel(const float* __restrict__ ent,
                                                   const float4* __restrict__ rot_v4,
                                                   float* __restrict__ out) {
    __shared__ v4h smem[4352];   // 34816 B: 8 zones x 4 KB + epilogue overlay

    const int tid  = threadIdx.x;      // 0..511
    const int lane = tid & 63;
    const int w    = tid >> 6;         // 0..7
    const int eb   = blockIdx.x * TE;
    const int eg   = lane & 7;         // entities 4eg..4eg+3
    const int bg   = lane >> 3;        // batches 4bg..4bg+3

    v4h* se = smem + w * 512;          // [32 ent rows][8 cols] v4h
    v4h* sr = se + 256;                // [32 batch rows][8 cols] v4h

    // staging maps (per wave, per chunk): 32 rows x 16 dims for ent AND rot
    const int srow = lane & 31;        // ent row / rot batch
    const int h    = lane >> 5;        // 0/1: which half of the quads/dpairs

    const int c0 = w * NCW;

    float4 pe[4];   // ent: re[q],im[q] for q = 2h, 2h+1
    float4 pr[4];   // rot: dpairs 4h..4h+3 (dim-interleaved float4)

    auto load_chunk = [&](int c) {     // dims [16c, 16c+16)
        const int dk = c * DK;
        int er = min(eb + srow, E_TOT - 1);
        const float* b0 = ent + (size_t)er * (2 * DIMH);
        #pragma unroll
        for (int s = 0; s < 2; ++s) {
            int q = 2 * h + s;
            pe[2 * s]     = *reinterpret_cast<const float4*>(b0 + dk + 4 * q);
            pe[2 * s + 1] = *reinterpret_cast<const float4*>(b0 + DIMH + dk + 4 * q);
        }
        #pragma unroll
        for (int s = 0; s < 4; ++s)
            pr[s] = rot_v4[srow * (DIMH / 2) + c * (DK / 2) + 4 * h + s];
    };

    auto store_chunk = [&]() {
        const int sw = (srow >> 2) & 7;
        #pragma unroll
        for (int s = 0; s < 2; ++s) {
            int q = 2 * h + s;
            v4h lo, hi;                              // (re,im,re,im) per 2 dims
            lo.xy = pkrtz(pe[2 * s].x, pe[2 * s + 1].x);
            lo.zw = pkrtz(pe[2 * s].y, pe[2 * s + 1].y);
            hi.xy = pkrtz(pe[2 * s].z, pe[2 * s + 1].z);
            hi.zw = pkrtz(pe[2 * s].w, pe[2 * s + 1].w);
            se[srow * 8 + ((2 * q)     ^ sw)] = lo;
            se[srow * 8 + ((2 * q + 1) ^ sw)] = hi;
        }
        #pragma unroll
        for (int s = 0; s < 4; ++s) {
            v4h r;                                   // already dim-interleaved
            r.xy = pkrtz(pr[s].x, pr[s].y);
            r.zw = pkrtz(pr[s].z, pr[s].w);
            sr[srow * 8 + ((4 * h + s) ^ sw)] = r;
        }
    };

    float acc[4][4];   // [batch j][entity k] f32 — static indices only
    #pragma unroll
    for (int j = 0; j < 4; ++j)
        #pragma unroll
        for (int k = 0; k < 4; ++k) acc[j][k] = 0.f;

    const v4h* sr_b = sr + (4 * bg) * 8;
    const v4h* se_b = se + (4 * eg) * 8;

    load_chunk(c0);

    #pragma unroll 1
    for (int cc = 0; cc < NCW; ++cc) {
        store_chunk();                            // regs (chunk c0+cc) -> LDS
        if (cc + 1 < NCW) load_chunk(c0 + cc + 1);

        #pragma unroll 4
        for (int p = 0; p < DK / 2; ++p) {
            int pb = p ^ bg, pk = p ^ eg;
            v4h r0 = sr_b[0 * 8 + pb];
            v4h r1 = sr_b[1 * 8 + pb];
            v4h r2 = sr_b[2 * 8 + pb];
            v4h r3 = sr_b[3 * 8 + pb];
            v4h e0 = se_b[0 * 8 + pk];
            v4h e1 = se_b[1 * 8 + pk];
            v4h e2 = se_b[2 * 8 + pk];
            v4h e3 = se_b[3 * 8 + pk];
            // per (pair, 2 dims): 2 pk_sub + 2 dot2 + 2 trans-sqrt(free) + adds
            #define CONTRIB(J, K, R, E)                                   \
                { v2h a = R.xy - E.xy;                                    \
                  v2h b = R.zw - E.zw;                                    \
                  float s0 = dot2(a, a, 0.f);                             \
                  float s1 = dot2(b, b, 0.f);                             \
                  acc[J][K] += __builtin_amdgcn_sqrtf(s0)                 \
                             + __builtin_amdgcn_sqrtf(s1); }
            CONTRIB(0,0,r0,e0) CONTRIB(0,1,r0,e1) CONTRIB(0,2,r0,e2) CONTRIB(0,3,r0,e3)
            CONTRIB(1,0,r1,e0) CONTRIB(1,1,r1,e1) CONTRIB(1,2,r1,e2) CONTRIB(1,3,r1,e3)
            CONTRIB(2,0,r2,e0) CONTRIB(2,1,r2,e1) CONTRIB(2,2,r2,e2) CONTRIB(2,3,r2,e3)
            CONTRIB(3,0,r3,e0) CONTRIB(3,1,r3,e1) CONTRIB(3,2,r3,e2) CONTRIB(3,3,r3,e3)
            #undef CONTRIB
        }
    }

    // ---- cross-wave reduction: 8 d-partials per (b,e) ----
    float part[16];
    #pragma unroll
    for (int j = 0; j < 4; ++j)
        #pragma unroll
        for (int k = 0; k < 4; ++k)
            part[j * 4 + k] = acc[j][k];

    __syncthreads();                       // all waves done with staging LDS
    float* red = (float*)smem;             // 512 x 17 floats = 34816 B, fits
    #pragma unroll
    for (int i = 0; i < 16; ++i)
        red[tid * 17 + i] = part[i];       // stride 17: 2 lanes/bank = free
    __syncthreads();

    // 1024 outputs, 2/thread; consecutive threads -> consecutive entities
    #pragma unroll
    for (int t = 0; t < 2; ++t) {
        int O  = tid + 512 * t;
        int b  = O >> 5;                   // 0..31
        int ei = O & 31;
        int e  = eb + ei;
        if (e < E_TOT) {
            int lane_src = ((b >> 2) << 3) + (ei >> 2);   // bg*8 + eg
            int idx      = ((b & 3) << 2) + (ei & 3);     // j*4 + k
            float sum = 0.f;
            #pragma unroll
            for (int w8 = 0; w8 < 8; ++w8)
                sum += red[(w8 * 64 + lane_src) * 17 + idx];
            out[(size_t)b * E_TOT + e] = 6.0f - sum;
        }
    }
}

extern "C" void kernel_launch(void* const* d_in, const int* in_sizes, int n_in,
                              void* d_out, int out_size, void* d_ws, size_t ws_size,
                              hipStream_t stream) {
    const float* head = (const float*)d_in[0];   // (32, 512)
    const float* rel  = (const float*)d_in[1];   // (32, 256)
    const float* ent  = (const float*)d_in[2];   // (43234, 512)
    float4* rot_v4 = (float4*)d_ws;              // 32 * 128 * 16 B = 64 KB

    rot_kernel<<<(NB * DIMH / 2) / 64, 64, 0, stream>>>(head, rel, rot_v4);

    int etiles = (E_TOT + TE - 1) / TE;          // 1352
    dist_kernel<<<etiles, 512, 0, stream>>>(ent, rot_v4, (float*)d_out);
}